// Round 1
// baseline (1290.979 us; speedup 1.0000x reference)
//
#include <hip/hip_runtime.h>
#include <hip/hip_bf16.h>
#include <stdint.h>

// Problem constants (VOCAB=32000, EMBED=512, HIDDEN=1024, ATT_L=64, MAX_LEN=32, BATCH=64)
#define T_STEPS 31        // MAX_LEN - 1
#define B_ 64
#define E_ 512
#define H_ 1024
#define G4 4096           // 4*HIDDEN gates
#define V_ 32000
#define MPAD 2048         // T_STEPS*B_=1984 padded to 128-multiple
#define NREC 64           // recurrence blocks = G4/64, one CU each

typedef __bf16 bf16x8_t __attribute__((ext_vector_type(8)));
typedef float f32x4_t __attribute__((ext_vector_type(4)));
typedef unsigned short u16x8_t __attribute__((ext_vector_type(8)));
using bf16 = __hip_bfloat16;

typedef const __attribute__((address_space(1))) unsigned int gas_u32;
typedef __attribute__((address_space(3))) unsigned int las_u32;

// Async global->LDS, 16B per lane. LDS dest must be wave-uniform base + lane*16
// (m104/m108: no per-lane scatter, no padding). Width=16 was the 517->874 TF step (m97).
__device__ __forceinline__ void async16(const bf16* g, bf16* l) {
    __builtin_amdgcn_global_load_lds((gas_u32*)(uintptr_t)g, (las_u32*)(uintptr_t)l, 16, 0, 0);
}

// ---------------------------------------------------------------------------
// m97-style GEMM: C = A @ BT^T (+bias) (+accumulate)
// 1D grid + bijective XCD swizzle (m204): 16 consecutive swizzled wgids share
// one B-panel AND one XCD-L2 -> B fetched once per XCD instead of ~4x.
// ---------------------------------------------------------------------------
template<int BM, int BN>
__global__ __launch_bounds__(256)
void gemm_lds(const bf16* __restrict__ A, const bf16* __restrict__ BT,
              float* __restrict__ C, const float* __restrict__ bias,
              int M, int N, int K, int accumulate, int mblocks)
{
    constexpr int BK = 32;
    constexpr int WM = BM / 2, WN = BN / 2;
    constexpr int MI = WM / 16, NI = WN / 16;
    constexpr int AV = (BM * BK) / (8 * 256);
    constexpr int BV = (BN * BK) / (8 * 256);
    static_assert(AV >= 1 && BV >= 1, "tile too small for staging");

    __shared__ bf16 As[BM * BK];
    __shared__ bf16 Bs[BN * BK];

    const int tid = threadIdx.x;
    const int lane = tid & 63;
    const int w = tid >> 6;
    const int wr = w >> 1, wc = w & 1;
    const int quad = lane >> 4, l16 = lane & 15;

    // bijective XCD swizzle (m204): contiguous wgid chunk per XCD
    const int nwg = gridDim.x;
    const int bid = blockIdx.x;
    const int q = nwg >> 3, r = nwg & 7;
    const int xcd = bid & 7, o = bid >> 3;
    const int wgid = (xcd < r ? xcd * (q + 1) : r * (q + 1) + (xcd - r) * q) + o;
    const int m0 = (wgid % mblocks) * BM;
    const int n0 = (wgid / mblocks) * BN;

    f32x4_t acc[MI][NI];
#pragma unroll
    for (int i = 0; i < MI; i++)
#pragma unroll
        for (int j = 0; j < NI; j++) acc[i][j] = f32x4_t{0.f, 0.f, 0.f, 0.f};

    for (int kt = 0; kt < K; kt += BK) {
#pragma unroll
        for (int v = 0; v < AV; v++) {
            int idx = tid + v * 256;
            int row = idx >> 2, col = (idx & 3) << 3;
            async16(A + (size_t)(m0 + row) * K + kt + col, As + idx * 8);
        }
#pragma unroll
        for (int v = 0; v < BV; v++) {
            int idx = tid + v * 256;
            int row = idx >> 2, col = (idx & 3) << 3;
            async16(BT + (size_t)(n0 + row) * K + kt + col, Bs + idx * 8);
        }
        __syncthreads();

        bf16x8_t af[MI], bfr[NI];
#pragma unroll
        for (int i = 0; i < MI; i++)
            af[i] = __builtin_bit_cast(bf16x8_t,
                *reinterpret_cast<const u16x8_t*>(&As[(wr * WM + i * 16 + l16) * BK + quad * 8]));
#pragma unroll
        for (int j = 0; j < NI; j++)
            bfr[j] = __builtin_bit_cast(bf16x8_t,
                *reinterpret_cast<const u16x8_t*>(&Bs[(wc * WN + j * 16 + l16) * BK + quad * 8]));
#pragma unroll
        for (int i = 0; i < MI; i++)
#pragma unroll
            for (int j = 0; j < NI; j++)
                acc[i][j] = __builtin_amdgcn_mfma_f32_16x16x32_bf16(af[i], bfr[j], acc[i][j], 0, 0, 0);
        __syncthreads();
    }

    // C/D layout: col=lane&15, row=quad*4+reg (m89)
#pragma unroll
    for (int i = 0; i < MI; i++) {
        int rbase = m0 + wr * WM + i * 16 + quad * 4;
#pragma unroll
        for (int j = 0; j < NI; j++) {
            int coln = n0 + wc * WN + j * 16 + l16;
            float badd = bias ? bias[coln] : 0.f;
#pragma unroll
            for (int r = 0; r < 4; r++) {
                int grow = rbase + r;
                if (grow < M) {
                    size_t ci = (size_t)grow * N + coln;
                    float val = acc[i][j][r] + badd;
                    if (accumulate) C[ci] += val; else C[ci] = val;
                }
            }
        }
    }
}

// ---------------------------------------------------------------------------
// Persistent recurrence kernel: all T_STEPS LSTM steps in one launch.
// 64 blocks (1/CU, LDS-bound), block n owns permuted gate cols [n*64, n*64+64).
// Whh slice (64x1024 bf16 = 128KB) lives in LDS for the whole kernel,
// XOR-swizzled byte^=(row&7)<<4 so the stride-2048B ds_read_b128 is ~2-way
// (free) instead of 16-way. h fragments are loaded global->VGPR directly
// (a lane's A-fragment is 16 contiguous bytes), so the K-loop has no barriers
// and the compiler pipelines all loads. Cell state c lives in registers.
// Steps are separated by a device-scope atomic grid barrier (64 blocks on
// 256 CUs are always co-resident; release/acquire fences handle cross-XCD L2).
// ---------------------------------------------------------------------------
__device__ __forceinline__ void grid_barrier(int* bar, int target) {
    __syncthreads();
    if (threadIdx.x == 0) {
        __threadfence();                       // release: publish hs[t] writes
        atomicAdd(bar, 1);                     // device-scope by default (m20)
        while (__hip_atomic_load(bar, __ATOMIC_ACQUIRE, __HIP_MEMORY_SCOPE_AGENT) < target)
            __builtin_amdgcn_s_sleep(2);
        __threadfence();                       // acquire: invalidate stale L1/L2
    }
    __syncthreads();
}

__global__ __launch_bounds__(256)
void recurrence(const bf16* __restrict__ h0, bf16* __restrict__ hs,
                const bf16* __restrict__ Whh, const float* __restrict__ pre_x,
                const float* __restrict__ ctxW, const float* __restrict__ bc,
                int* __restrict__ bar)
{
    __shared__ bf16 Wl[64 * H_];          // 128 KiB swizzled Whh slice
    __shared__ float gates[64 * 65];      // 16.6 KiB (+1 pad)  -> 147.7 KiB total

    const int tid = threadIdx.x;
    const int lane = tid & 63;
    const int w = tid >> 6;
    const int wr = w >> 1, wc = w & 1;          // 2x2 waves, wave tile 32x32
    const int quad = lane >> 4, l16 = lane & 15;
    const int n0 = blockIdx.x * 64;

    // ---- one-time: Whh slice -> LDS, reg-staged swizzled write (rule 21) ----
#pragma unroll 4
    for (int ck = tid; ck < 64 * 128; ck += 256) {          // 16B chunks
        int row = ck >> 7, c16 = ck & 127;
        u16x8_t v = *reinterpret_cast<const u16x8_t*>(Whh + (size_t)(n0 + row) * H_ + (c16 << 3));
        int byte = (row << 11) + (((c16 << 4)) ^ ((row & 7) << 4));
        *reinterpret_cast<u16x8_t*>(reinterpret_cast<char*>(Wl) + byte) = v;
    }

    float creg[4] = {0.f, 0.f, 0.f, 0.f};    // cell state, 4 (b,jj) items/thread
    __syncthreads();

    // lane-invariant address pieces
    const int arow = wr * 32 + l16;           // A-fragment row (i adds 16)
    const int r0 = wc * 32 + l16;             // B-fragment row (j adds 16; r&7 invariant)
    const int xr = (r0 & 7) << 4;
    const char* wl0 = reinterpret_cast<const char*>(Wl) + (r0 << 11);
    const char* wl1 = reinterpret_cast<const char*>(Wl) + ((r0 + 16) << 11);

    int target = NREC;
    for (int t = 0; t < T_STEPS; t++) {
        const bf16* hp = t ? hs + (size_t)(t - 1) * B_ * H_ : h0;
        const bf16* ha0 = hp + (size_t)arow * H_ + quad * 8;
        const bf16* ha1 = ha0 + 16 * H_;

        f32x4_t acc[2][2];
#pragma unroll
        for (int i = 0; i < 2; i++)
#pragma unroll
            for (int j = 0; j < 2; j++) acc[i][j] = f32x4_t{0.f, 0.f, 0.f, 0.f};

        // barrier-free K loop: 64 global 16B loads + 64 ds_read_b128 + 128 MFMA per lane
#pragma unroll 4
        for (int kt = 0; kt < H_; kt += 32) {
            int off = ((kt << 1) + (quad << 4)) ^ xr;
            bf16x8_t a0 = __builtin_bit_cast(bf16x8_t, *reinterpret_cast<const u16x8_t*>(ha0 + kt));
            bf16x8_t a1 = __builtin_bit_cast(bf16x8_t, *reinterpret_cast<const u16x8_t*>(ha1 + kt));
            bf16x8_t b0 = __builtin_bit_cast(bf16x8_t, *reinterpret_cast<const u16x8_t*>(wl0 + off));
            bf16x8_t b1 = __builtin_bit_cast(bf16x8_t, *reinterpret_cast<const u16x8_t*>(wl1 + off));
            acc[0][0] = __builtin_amdgcn_mfma_f32_16x16x32_bf16(a0, b0, acc[0][0], 0, 0, 0);
            acc[0][1] = __builtin_amdgcn_mfma_f32_16x16x32_bf16(a0, b1, acc[0][1], 0, 0, 0);
            acc[1][0] = __builtin_amdgcn_mfma_f32_16x16x32_bf16(a1, b0, acc[1][0], 0, 0, 0);
            acc[1][1] = __builtin_amdgcn_mfma_f32_16x16x32_bf16(a1, b1, acc[1][1], 0, 0, 0);
        }

        // gate assembly into LDS (identical arithmetic order to old step_fused)
#pragma unroll
        for (int i = 0; i < 2; i++) {
            int rbase = wr * 32 + i * 16 + quad * 4;
#pragma unroll
            for (int j = 0; j < 2; j++) {
                int col = wc * 32 + j * 16 + l16;
                int gcol = n0 + col;
                float badd = bc[gcol];
#pragma unroll
                for (int r = 0; r < 4; r++) {
                    int b = rbase + r;
                    gates[b * 65 + col] = acc[i][j][r] + badd
                        + pre_x[((size_t)t * B_ + b) * G4 + gcol]
                        + ctxW[(size_t)b * G4 + gcol];
                }
            }
        }
        __syncthreads();

        // LSTM pointwise: 64 b x 16 j per block, 4 items/thread, c in registers
#pragma unroll
        for (int v = 0; v < 4; v++) {
            int item = tid + v * 256;
            int b = item >> 4, jj = item & 15;
            float gi = gates[b * 65 + jj * 4 + 0];
            float gf = gates[b * 65 + jj * 4 + 1];
            float gg = gates[b * 65 + jj * 4 + 2];
            float go = gates[b * 65 + jj * 4 + 3];
            int j = (n0 >> 2) + jj;
            float si = 1.f / (1.f + expf(-gi));
            float sf = 1.f / (1.f + expf(-gf));
            float so = 1.f / (1.f + expf(-go));
            float cn = sf * creg[v] + si * tanhf(gg);
            float hn = so * tanhf(cn);
            creg[v] = cn;
            hs[((size_t)t * B_ + b) * H_ + j] = __float2bfloat16(hn);
        }

        grid_barrier(bar, target);
        target += NREC;
    }
}

// ---------------------------------------------------------------------------
// Prep kernels
// ---------------------------------------------------------------------------

// ctx[b] = sum_l features[b][l][:] (softmax over singleton dim == uniform). hi/lo bf16 split.
__global__ void ctx_kernel(const float* __restrict__ features, bf16* __restrict__ hi, bf16* __restrict__ lo)
{
    int b = blockIdx.x;
    for (int j = threadIdx.x; j < H_; j += 256) {
        float s = 0.f;
        const float* f = features + (size_t)b * 64 * H_ + j;
#pragma unroll
        for (int l = 0; l < 64; l++) s += f[(size_t)l * H_];
        bf16 h = __float2bfloat16(s);
        hi[b * H_ + j] = h;
        lo[b * H_ + j] = __float2bfloat16(s - __bfloat162float(h));
    }
}

// bc[perm(g)] = b_ih[g] + b_hh[g], perm(g) = (g%H)*4 + g/H
__global__ void bias_kernel(const float* __restrict__ bi, const float* __restrict__ bh, float* __restrict__ bc)
{
    int g = blockIdx.x * 256 + threadIdx.x;
    if (g < G4) bc[(g & (H_ - 1)) * 4 + (g >> 10)] = bi[g] + bh[g];
}

// xs[t*B+b][e] = bf16(embed[captions[b][t]][e]); pad rows zeroed
__global__ void gather_embed(const int* __restrict__ captions, const float* __restrict__ table,
                             bf16* __restrict__ xs)
{
    int idx = blockIdx.x * 256 + threadIdx.x;   // < MPAD*E_
    int tb = idx >> 9, e = idx & (E_ - 1);
    float v = 0.f;
    if (tb < T_STEPS * B_) {
        int t = tb >> 6, b = tb & 63;
        int tok = captions[b * 32 + t];
        v = table[(size_t)tok * E_ + e];
    }
    xs[idx] = __float2bfloat16(v);
}

// fp32 (rows x cols slice of strided src) -> bf16 (+optional lo residual), optional gate-row permute
__global__ void cvt_bf16(const float* __restrict__ src, bf16* __restrict__ hi, bf16* __restrict__ lo,
                         int rows, int cols, int stride, int off, int perm)
{
    long i4 = (long)blockIdx.x * 256 + threadIdx.x;
    long total = (long)rows * cols / 4;
    if (i4 >= total) return;
    long e = i4 * 4;
    int r = (int)(e / cols);
    int ci = (int)(e % cols);
    int ro = perm ? ((r & (H_ - 1)) * 4 + (r >> 10)) : r;
    f32x4_t v = *reinterpret_cast<const f32x4_t*>(src + (size_t)r * stride + off + ci);
    size_t ob = (size_t)ro * cols + ci;
#pragma unroll
    for (int q = 0; q < 4; q++) {
        bf16 h = __float2bfloat16(v[q]);
        hi[ob + q] = h;
        if (lo) lo[ob + q] = __float2bfloat16(v[q] - __bfloat162float(h));
    }
}

__global__ void zero_f32(float* __restrict__ p, int n)
{
    int i = blockIdx.x * 256 + threadIdx.x;
    if (i < n) p[i] = 0.f;
}
__global__ void zero_bf16(bf16* __restrict__ p, int n)
{
    int i = blockIdx.x * 256 + threadIdx.x;
    if (i < n) p[i] = __float2bfloat16(0.f);
}

// ---------------------------------------------------------------------------
extern "C" void kernel_launch(void* const* d_in, const int* in_sizes, int n_in,
                              void* d_out, int out_size, void* d_ws, size_t ws_size,
                              hipStream_t stream)
{
    (void)in_sizes; (void)n_in; (void)out_size; (void)ws_size;
    const float* features = (const float*)d_in[0];
    const int*   captions = (const int*)d_in[1];
    // d_in[2] lengths unused (full). d_in[8]/d_in[9] attn_W/b: dead (softmax over singleton dim).
    const float* embed    = (const float*)d_in[3];
    const float* W_ih     = (const float*)d_in[4];
    const float* W_hh     = (const float*)d_in[5];
    const float* b_ih     = (const float*)d_in[6];
    const float* b_hh     = (const float*)d_in[7];
    const float* lin_W    = (const float*)d_in[10];
    const float* lin_b    = (const float*)d_in[11];
    float* out = (float*)d_out;

    char* wp = (char*)d_ws;
    auto alloc = [&](size_t bytes) -> void* {
        void* p = (void*)wp;
        wp += (bytes + 255) & ~(size_t)255;
        return p;
    };
    bf16*  ctx_hi = (bf16*)alloc((size_t)B_ * H_ * 2);
    bf16*  ctx_lo = (bf16*)alloc((size_t)B_ * H_ * 2);
    float* bc     = (float*)alloc((size_t)G4 * 4);
    bf16*  xs     = (bf16*)alloc((size_t)MPAD * E_ * 2);
    bf16*  Wx     = (bf16*)alloc((size_t)G4 * E_ * 2);      // gate-permuted rows
    bf16*  Wc_hi  = (bf16*)alloc((size_t)G4 * H_ * 2);      // gate-permuted rows
    bf16*  Wc_lo  = (bf16*)alloc((size_t)G4 * H_ * 2);
    bf16*  Whh    = (bf16*)alloc((size_t)G4 * H_ * 2);      // gate-permuted rows
    bf16*  WlinB  = (bf16*)alloc((size_t)V_ * H_ * 2);
    float* pre_x  = (float*)alloc((size_t)T_STEPS * B_ * G4 * 4);  // permuted cols
    float* ctxW   = (float*)alloc((size_t)B_ * G4 * 4);            // permuted cols
    bf16*  h0     = (bf16*)alloc((size_t)B_ * H_ * 2);             // zero initial h
    bf16*  hs     = (bf16*)alloc((size_t)MPAD * H_ * 2);
    int*   bar    = (int*)alloc(256);                              // grid barrier counter

    // ---- prep (re-run every call: ws re-poisoned before each timed launch) ----
    bias_kernel<<<16, 256, 0, stream>>>(b_ih, b_hh, bc);
    ctx_kernel<<<B_, 256, 0, stream>>>(features, ctx_hi, ctx_lo);
    gather_embed<<<MPAD * E_ / 256, 256, 0, stream>>>(captions, embed, xs);
    cvt_bf16<<<G4 * E_ / 4 / 256, 256, 0, stream>>>(W_ih, Wx, nullptr, G4, E_, E_ + H_, 0, 1);
    cvt_bf16<<<G4 * H_ / 4 / 256, 256, 0, stream>>>(W_ih, Wc_hi, Wc_lo, G4, H_, E_ + H_, E_, 1);
    cvt_bf16<<<G4 * H_ / 4 / 256, 256, 0, stream>>>(W_hh, Whh, nullptr, G4, H_, H_, 0, 1);
    cvt_bf16<<<V_ * (H_ / 4) / 256, 256, 0, stream>>>(lin_W, WlinB, nullptr, V_, H_, H_, 0, 0);
    zero_bf16<<<B_ * H_ / 256, 256, 0, stream>>>(h0, B_ * H_);
    zero_bf16<<<(MPAD - T_STEPS * B_) * H_ / 256, 256, 0, stream>>>(
        hs + (size_t)T_STEPS * B_ * H_, (MPAD - T_STEPS * B_) * H_);
    zero_f32<<<1, 256, 0, stream>>>((float*)bar, 1);

    // ---- ctxW (once; hi/lo split kills systematic bf16 error on ctx path) ----
    gemm_lds<64, 64><<<G4 / 64, 256, 0, stream>>>(ctx_hi, Wc_hi, ctxW, nullptr, B_, G4, H_, 0, 1);
    gemm_lds<64, 64><<<G4 / 64, 256, 0, stream>>>(ctx_lo, Wc_hi, ctxW, nullptr, B_, G4, H_, 1, 1);
    gemm_lds<64, 64><<<G4 / 64, 256, 0, stream>>>(ctx_hi, Wc_lo, ctxW, nullptr, B_, G4, H_, 1, 1);

    // ---- pre_x = xs @ Wx^T for all steps (M=1984, N=4096, K=512) ----
    gemm_lds<128, 128><<<(MPAD / 128) * (G4 / 128), 256, 0, stream>>>(
        xs, Wx, pre_x, nullptr, T_STEPS * B_, G4, E_, 0, MPAD / 128);

    // ---- recurrence: ONE persistent kernel, grid barrier between steps ----
    recurrence<<<NREC, 256, 0, stream>>>(h0, hs, Whh, pre_x, ctxW, bc, bar);

    // ---- logits = hs @ lin_W^T + lin_b (M=1984, N=32000, K=1024) ----
    gemm_lds<128, 128><<<(MPAD / 128) * (V_ / 128), 256, 0, stream>>>(
        hs, WlinB, out, lin_b, T_STEPS * B_, V_, H_, 0, MPAD / 128);
}

// Round 2
// 1144.478 us; speedup vs baseline: 1.1280x; 1.1280x over previous
//
#include <hip/hip_runtime.h>
#include <hip/hip_bf16.h>
#include <stdint.h>

// Problem constants (VOCAB=32000, EMBED=512, HIDDEN=1024, ATT_L=64, MAX_LEN=32, BATCH=64)
#define T_STEPS 31        // MAX_LEN - 1
#define B_ 64
#define E_ 512
#define H_ 1024
#define G4 4096           // 4*HIDDEN gates
#define V_ 32000
#define MPAD 2048         // T_STEPS*B_=1984 padded to 128-multiple
#define NREC 64           // recurrence blocks = G4/64, one CU each

typedef __bf16 bf16x8_t __attribute__((ext_vector_type(8)));
typedef float f32x4_t __attribute__((ext_vector_type(4)));
typedef unsigned short u16x8_t __attribute__((ext_vector_type(8)));
using bf16 = __hip_bfloat16;

typedef const __attribute__((address_space(1))) unsigned int gas_u32;
typedef __attribute__((address_space(3))) unsigned int las_u32;

// Async global->LDS, 16B per lane. LDS dest must be wave-uniform base + lane*16
// (m104/m108: no per-lane scatter, no padding). Width=16 was the 517->874 TF step (m97).
__device__ __forceinline__ void async16(const bf16* g, bf16* l) {
    __builtin_amdgcn_global_load_lds((gas_u32*)(uintptr_t)g, (las_u32*)(uintptr_t)l, 16, 0, 0);
}

// ---------------------------------------------------------------------------
// m97-style GEMM: C = A @ BT^T (+bias) (+accumulate)
// 1D grid + bijective XCD swizzle (m204): consecutive swizzled wgids share
// one B-panel AND one XCD-L2 -> B fetched ~once per XCD.
// ---------------------------------------------------------------------------
template<int BM, int BN>
__global__ __launch_bounds__(256)
void gemm_lds(const bf16* __restrict__ A, const bf16* __restrict__ BT,
              float* __restrict__ C, const float* __restrict__ bias,
              int M, int N, int K, int accumulate, int mblocks)
{
    constexpr int BK = 32;
    constexpr int WM = BM / 2, WN = BN / 2;
    constexpr int MI = WM / 16, NI = WN / 16;
    constexpr int AV = (BM * BK) / (8 * 256);
    constexpr int BV = (BN * BK) / (8 * 256);
    static_assert(AV >= 1 && BV >= 1, "tile too small for staging");

    __shared__ bf16 As[BM * BK];
    __shared__ bf16 Bs[BN * BK];

    const int tid = threadIdx.x;
    const int lane = tid & 63;
    const int w = tid >> 6;
    const int wr = w >> 1, wc = w & 1;
    const int quad = lane >> 4, l16 = lane & 15;

    // bijective XCD swizzle (m204)
    const int nwg = gridDim.x;
    const int bid = blockIdx.x;
    const int q = nwg >> 3, r = nwg & 7;
    const int xcd = bid & 7, o = bid >> 3;
    const int wgid = (xcd < r ? xcd * (q + 1) : r * (q + 1) + (xcd - r) * q) + o;
    const int m0 = (wgid % mblocks) * BM;
    const int n0 = (wgid / mblocks) * BN;

    f32x4_t acc[MI][NI];
#pragma unroll
    for (int i = 0; i < MI; i++)
#pragma unroll
        for (int j = 0; j < NI; j++) acc[i][j] = f32x4_t{0.f, 0.f, 0.f, 0.f};

    for (int kt = 0; kt < K; kt += BK) {
#pragma unroll
        for (int v = 0; v < AV; v++) {
            int idx = tid + v * 256;
            int row = idx >> 2, col = (idx & 3) << 3;
            async16(A + (size_t)(m0 + row) * K + kt + col, As + idx * 8);
        }
#pragma unroll
        for (int v = 0; v < BV; v++) {
            int idx = tid + v * 256;
            int row = idx >> 2, col = (idx & 3) << 3;
            async16(BT + (size_t)(n0 + row) * K + kt + col, Bs + idx * 8);
        }
        __syncthreads();

        bf16x8_t af[MI], bfr[NI];
#pragma unroll
        for (int i = 0; i < MI; i++)
            af[i] = __builtin_bit_cast(bf16x8_t,
                *reinterpret_cast<const u16x8_t*>(&As[(wr * WM + i * 16 + l16) * BK + quad * 8]));
#pragma unroll
        for (int j = 0; j < NI; j++)
            bfr[j] = __builtin_bit_cast(bf16x8_t,
                *reinterpret_cast<const u16x8_t*>(&Bs[(wc * WN + j * 16 + l16) * BK + quad * 8]));
#pragma unroll
        for (int i = 0; i < MI; i++)
#pragma unroll
            for (int j = 0; j < NI; j++)
                acc[i][j] = __builtin_amdgcn_mfma_f32_16x16x32_bf16(af[i], bfr[j], acc[i][j], 0, 0, 0);
        __syncthreads();
    }

    // C/D layout: col=lane&15, row=quad*4+reg (m89)
#pragma unroll
    for (int i = 0; i < MI; i++) {
        int rbase = m0 + wr * WM + i * 16 + quad * 4;
#pragma unroll
        for (int j = 0; j < NI; j++) {
            int coln = n0 + wc * WN + j * 16 + l16;
            float badd = bias ? bias[coln] : 0.f;
#pragma unroll
            for (int r = 0; r < 4; r++) {
                int grow = rbase + r;
                if (grow < M) {
                    size_t ci = (size_t)grow * N + coln;
                    float val = acc[i][j][r] + badd;
                    if (accumulate) C[ci] += val; else C[ci] = val;
                }
            }
        }
    }
}

// ---------------------------------------------------------------------------
// Grid barrier (device-scope). The agent-scope fences invalidate per-XCD L2 --
// everything re-read per step must therefore live in registers or LDS.
// ---------------------------------------------------------------------------
__device__ __forceinline__ void grid_barrier(int* bar, int target) {
    __syncthreads();
    if (threadIdx.x == 0) {
        __threadfence();                       // release: publish hs[t] writes
        atomicAdd(bar, 1);                     // device-scope by default (m20)
        while (__hip_atomic_load(bar, __ATOMIC_ACQUIRE, __HIP_MEMORY_SCOPE_AGENT) < target)
            __builtin_amdgcn_s_sleep(2);
        __threadfence();                       // acquire: invalidate stale caches
    }
    __syncthreads();
}

// ---------------------------------------------------------------------------
// Persistent recurrence v2: 64 blocks x 512 threads (8 waves = 2/SIMD).
// Block n owns permuted gate cols [n*64, n*64+64). Whh slice (128KB) in LDS,
// XOR-swizzled. Per step: h loaded global->VGPR (fully unrolled K-loop ->
// compiler hoists ~all 32 independent 16B loads -> ~256 lines in flight/CU).
// ctxW+bc hoisted to registers ONCE (immune to the per-barrier L2 invalidate);
// pre_x[t] prefetched into registers before the K-loop. Gate sum done in the
// pointwise phase in the exact original fp32 order (acc + bc + pre_x + ctxW).
// ---------------------------------------------------------------------------
__global__ __launch_bounds__(512)
void recurrence(const bf16* __restrict__ h0, bf16* __restrict__ hs,
                const bf16* __restrict__ Whh, const float* __restrict__ pre_x,
                const float* __restrict__ ctxW, const float* __restrict__ bc,
                int* __restrict__ bar)
{
    __shared__ bf16 Wl[64 * H_];          // 128 KiB swizzled Whh slice
    __shared__ float gates[64 * 68];      // 17 KiB raw acc exchange (68: aligned + bank-spread)

    const int tid = threadIdx.x;
    const int lane = tid & 63;
    const int w = tid >> 6;               // 0..7
    const int wr = w >> 1;                // 0..3: 16-row batch strip
    const int wc = w & 1;                 // 0..1: 32-col gate strip
    const int quad = lane >> 4, l16 = lane & 15;
    const int n0 = blockIdx.x * 64;

    // ---- one-time: Whh slice -> LDS, reg-staged swizzled write (rule 21) ----
#pragma unroll 4
    for (int ck = tid; ck < 64 * 128; ck += 512) {          // 16B chunks
        int row = ck >> 7, c16 = ck & 127;
        u16x8_t v = *reinterpret_cast<const u16x8_t*>(Whh + (size_t)(n0 + row) * H_ + (c16 << 3));
        int byte = (row << 11) + (((c16 << 4)) ^ ((row & 7) << 4));
        *reinterpret_cast<u16x8_t*>(reinterpret_cast<char*>(Wl) + byte) = v;
    }

    // ---- pointwise-phase constants hoisted to registers (survive L2 inval) ----
    const int pb = tid >> 3;              // batch row 0..63
    const int pj = tid & 7;               // gate-group pair 0..7 (j = pj*2, pj*2+1)
    const float* cxp = ctxW + (size_t)pb * G4 + n0 + pj * 8;
    const f32x4_t cx0 = *reinterpret_cast<const f32x4_t*>(cxp);
    const f32x4_t cx1 = *reinterpret_cast<const f32x4_t*>(cxp + 4);
    const f32x4_t bc0 = *reinterpret_cast<const f32x4_t*>(bc + n0 + pj * 8);
    const f32x4_t bc1 = *reinterpret_cast<const f32x4_t*>(bc + n0 + pj * 8 + 4);
    float creg0 = 0.f, creg1 = 0.f;       // cell state in registers

    __syncthreads();

    // lane-invariant address pieces
    const int arow = wr * 16 + l16;                   // A row (batch)
    const int r0 = wc * 32 + l16;                     // B row (gate col), r1 = r0+16
    const int xr = (r0 & 7) << 4;                     // (r0+16)&7 == r0&7
    const char* wl0 = reinterpret_cast<const char*>(Wl) + (r0 << 11);
    const char* wl1 = reinterpret_cast<const char*>(Wl) + ((r0 + 16) << 11);

    int target = NREC;
    for (int t = 0; t < T_STEPS; t++) {
        // prefetch pre_x[t] into regs; latency hides under the K-loop
        const float* px = pre_x + ((size_t)t * B_ + pb) * G4 + n0 + pj * 8;
        f32x4_t p0 = *reinterpret_cast<const f32x4_t*>(px);
        f32x4_t p1 = *reinterpret_cast<const f32x4_t*>(px + 4);

        const bf16* hp = t ? hs + (size_t)(t - 1) * B_ * H_ : h0;
        const bf16* ha = hp + (size_t)arow * H_ + quad * 8;

        f32x4_t acc0 = {0.f, 0.f, 0.f, 0.f}, acc1 = {0.f, 0.f, 0.f, 0.f};

        // barrier-free K loop, fully unrolled: 32 indep global 16B loads get
        // hoisted -> max outstanding lines; 64 ds_read_b128 + 64 MFMA per lane
#pragma unroll
        for (int kt = 0; kt < H_; kt += 32) {
            int off = ((kt << 1) + (quad << 4)) ^ xr;
            bf16x8_t a  = __builtin_bit_cast(bf16x8_t, *reinterpret_cast<const u16x8_t*>(ha + kt));
            bf16x8_t b0 = __builtin_bit_cast(bf16x8_t, *reinterpret_cast<const u16x8_t*>(wl0 + off));
            bf16x8_t b1 = __builtin_bit_cast(bf16x8_t, *reinterpret_cast<const u16x8_t*>(wl1 + off));
            acc0 = __builtin_amdgcn_mfma_f32_16x16x32_bf16(a, b0, acc0, 0, 0, 0);
            acc1 = __builtin_amdgcn_mfma_f32_16x16x32_bf16(a, b1, acc1, 0, 0, 0);
        }

        // raw acc -> LDS exchange (sum happens in pointwise phase, same order)
        {
            int rbase = wr * 16 + quad * 4;
#pragma unroll
            for (int r = 0; r < 4; r++) {
                gates[(rbase + r) * 68 + wc * 32 + l16]      = acc0[r];
                gates[(rbase + r) * 68 + wc * 32 + 16 + l16] = acc1[r];
            }
        }
        __syncthreads();

        // LSTM pointwise: thread -> (b=pb, jj=pj*2 / pj*2+1), c in registers
        {
            f32x4_t g0 = *reinterpret_cast<const f32x4_t*>(&gates[pb * 68 + pj * 8]);
            f32x4_t g1 = *reinterpret_cast<const f32x4_t*>(&gates[pb * 68 + pj * 8 + 4]);
            // exact original order: ((acc + bc) + pre_x) + ctxW
            float gi0 = g0[0] + bc0[0] + p0[0] + cx0[0];
            float gf0 = g0[1] + bc0[1] + p0[1] + cx0[1];
            float gg0 = g0[2] + bc0[2] + p0[2] + cx0[2];
            float go0 = g0[3] + bc0[3] + p0[3] + cx0[3];
            float gi1 = g1[0] + bc1[0] + p1[0] + cx1[0];
            float gf1 = g1[1] + bc1[1] + p1[1] + cx1[1];
            float gg1 = g1[2] + bc1[2] + p1[2] + cx1[2];
            float go1 = g1[3] + bc1[3] + p1[3] + cx1[3];

            float si0 = 1.f / (1.f + expf(-gi0));
            float sf0 = 1.f / (1.f + expf(-gf0));
            float so0 = 1.f / (1.f + expf(-go0));
            float cn0 = sf0 * creg0 + si0 * tanhf(gg0);
            float hn0 = so0 * tanhf(cn0);
            creg0 = cn0;

            float si1 = 1.f / (1.f + expf(-gi1));
            float sf1 = 1.f / (1.f + expf(-gf1));
            float so1 = 1.f / (1.f + expf(-go1));
            float cn1 = sf1 * creg1 + si1 * tanhf(gg1);
            float hn1 = so1 * tanhf(cn1);
            creg1 = cn1;

            int j0 = (n0 >> 2) + pj * 2;
            ushort2 hv;
            hv.x = __builtin_bit_cast(unsigned short, __float2bfloat16(hn0));
            hv.y = __builtin_bit_cast(unsigned short, __float2bfloat16(hn1));
            *reinterpret_cast<ushort2*>(&hs[((size_t)t * B_ + pb) * H_ + j0]) = hv;
        }

        if (t < T_STEPS - 1) {
            grid_barrier(bar, target);
            target += NREC;
        }
        // last step: kernel-end release makes hs visible to the final GEMM
    }
}

// ---------------------------------------------------------------------------
// Fused prep kernels (dispatch-count reduction: 19 -> 6 launches total)
// ---------------------------------------------------------------------------

// ctx + bias + gather_embed + zeros + bar reset, range-dispatched on blockIdx
__global__ __launch_bounds__(256)
void prep_misc(const float* __restrict__ features, const int* __restrict__ captions,
               const float* __restrict__ embed, const float* __restrict__ b_ih,
               const float* __restrict__ b_hh, bf16* __restrict__ ctxcat,
               float* __restrict__ bc, bf16* __restrict__ xs, bf16* __restrict__ h0,
               bf16* __restrict__ hs_tail, int* __restrict__ bar)
{
    const int blk = blockIdx.x, tid = threadIdx.x;
    if (blk < 64) {                       // ctx: A' = [hi | lo | hi] per batch row
        int b = blk;
        for (int j = tid; j < H_; j += 256) {
            float s = 0.f;
            const float* f = features + (size_t)b * 64 * H_ + j;
#pragma unroll
            for (int l = 0; l < 64; l++) s += f[(size_t)l * H_];
            bf16 h = __float2bfloat16(s);
            bf16 lo = __float2bfloat16(s - __bfloat162float(h));
            ctxcat[(size_t)b * 3072 + j] = h;
            ctxcat[(size_t)b * 3072 + 1024 + j] = lo;
            ctxcat[(size_t)b * 3072 + 2048 + j] = h;
        }
    } else if (blk < 80) {                // bias: bc[perm(g)] = b_ih[g]+b_hh[g]
        int g = (blk - 64) * 256 + tid;
        bc[(g & (H_ - 1)) * 4 + (g >> 10)] = b_ih[g] + b_hh[g];
    } else if (blk < 4176) {              // gather_embed; pad rows zeroed
        int idx = (blk - 80) * 256 + tid;
        int tb = idx >> 9, e = idx & (E_ - 1);
        float v = 0.f;
        if (tb < T_STEPS * B_) {
            int t = tb >> 6, b = tb & 63;
            v = embed[(size_t)captions[b * 32 + t] * E_ + e];
        }
        xs[idx] = __float2bfloat16(v);
    } else if (blk < 4432) {              // zero h0 (64K elems)
        h0[(blk - 4176) * 256 + tid] = __float2bfloat16(0.f);
    } else if (blk < 4688) {              // zero hs pad tail (64K elems)
        hs_tail[(blk - 4432) * 256 + tid] = __float2bfloat16(0.f);
    } else if (tid == 0) {
        *bar = 0;
    }
}

__device__ __forceinline__ void cvt4(const float* __restrict__ src, bf16* hi, bf16* hi2, bf16* lo)
{
    f32x4_t v = *reinterpret_cast<const f32x4_t*>(src);
#pragma unroll
    for (int q = 0; q < 4; q++) {
        bf16 h = __float2bfloat16(v[q]);
        hi[q] = h;
        if (hi2) hi2[q] = h;
        if (lo) lo[q] = __float2bfloat16(v[q] - __bfloat162float(h));
    }
}

// all weight conversions in ONE launch: Wx, Wc_cat ([Wc_hi|Wc_hi|Wc_lo]), Whh, WlinB
__global__ __launch_bounds__(256)
void prep_weights(const float* __restrict__ W_ih, const float* __restrict__ W_hh,
                  const float* __restrict__ lin_W, bf16* __restrict__ Wx,
                  bf16* __restrict__ Wc_cat, bf16* __restrict__ Whh, bf16* __restrict__ WlinB)
{
    const int blk = blockIdx.x;
    if (blk < 2048) {                     // Wx: 4096x512 of W_ih, gate-permuted
        int item = blk * 256 + threadIdx.x;
        int e = item * 4; int r = e >> 9; int ci = e & (E_ - 1);
        int ro = (r & (H_ - 1)) * 4 + (r >> 10);
        cvt4(W_ih + (size_t)r * (E_ + H_) + ci, Wx + (size_t)ro * E_ + ci, nullptr, nullptr);
    } else if (blk < 6144) {              // Wc: 4096x1024 slice, hi dup + lo residual
        int item = (blk - 2048) * 256 + threadIdx.x;
        int e = item * 4; int r = e >> 10; int ci = e & (H_ - 1);
        int ro = (r & (H_ - 1)) * 4 + (r >> 10);
        bf16* base = Wc_cat + (size_t)ro * 3072 + ci;
        cvt4(W_ih + (size_t)r * (E_ + H_) + E_ + ci, base, base + 1024, base + 2048);
    } else if (blk < 10240) {             // Whh: 4096x1024, gate-permuted
        int item = (blk - 6144) * 256 + threadIdx.x;
        int e = item * 4; int r = e >> 10; int ci = e & (H_ - 1);
        int ro = (r & (H_ - 1)) * 4 + (r >> 10);
        cvt4(W_hh + (size_t)r * H_ + ci, Whh + (size_t)ro * H_ + ci, nullptr, nullptr);
    } else {                              // WlinB: 32000x1024, no permute
        long item = (long)(blk - 10240) * 256 + threadIdx.x;
        long e = item * 4; int r = (int)(e >> 10); int ci = (int)(e & (H_ - 1));
        cvt4(lin_W + (size_t)r * H_ + ci, WlinB + (size_t)r * H_ + ci, nullptr, nullptr);
    }
}

// ---------------------------------------------------------------------------
extern "C" void kernel_launch(void* const* d_in, const int* in_sizes, int n_in,
                              void* d_out, int out_size, void* d_ws, size_t ws_size,
                              hipStream_t stream)
{
    (void)in_sizes; (void)n_in; (void)out_size; (void)ws_size;
    const float* features = (const float*)d_in[0];
    const int*   captions = (const int*)d_in[1];
    // d_in[2] lengths unused (full). d_in[8]/d_in[9] attn_W/b: dead (softmax over singleton dim).
    const float* embed    = (const float*)d_in[3];
    const float* W_ih     = (const float*)d_in[4];
    const float* W_hh     = (const float*)d_in[5];
    const float* b_ih     = (const float*)d_in[6];
    const float* b_hh     = (const float*)d_in[7];
    const float* lin_W    = (const float*)d_in[10];
    const float* lin_b    = (const float*)d_in[11];
    float* out = (float*)d_out;

    char* wp = (char*)d_ws;
    auto alloc = [&](size_t bytes) -> void* {
        void* p = (void*)wp;
        wp += (bytes + 255) & ~(size_t)255;
        return p;
    };
    bf16*  ctxcat = (bf16*)alloc((size_t)B_ * 3072 * 2);           // [hi | lo | hi]
    float* bc     = (float*)alloc((size_t)G4 * 4);
    bf16*  xs     = (bf16*)alloc((size_t)MPAD * E_ * 2);
    bf16*  Wx     = (bf16*)alloc((size_t)G4 * E_ * 2);             // gate-permuted rows
    bf16*  Wc_cat = (bf16*)alloc((size_t)G4 * 3072 * 2);           // [Wc_hi|Wc_hi|Wc_lo]
    bf16*  Whh    = (bf16*)alloc((size_t)G4 * H_ * 2);             // gate-permuted rows
    bf16*  WlinB  = (bf16*)alloc((size_t)V_ * H_ * 2);
    float* pre_x  = (float*)alloc((size_t)T_STEPS * B_ * G4 * 4);  // permuted cols
    float* ctxW   = (float*)alloc((size_t)B_ * G4 * 4);            // permuted cols
    bf16*  h0     = (bf16*)alloc((size_t)B_ * H_ * 2);             // zero initial h
    bf16*  hs     = (bf16*)alloc((size_t)MPAD * H_ * 2);
    int*   bar    = (int*)alloc(256);                              // grid barrier counter

    // ---- fused prep (2 launches) ----
    prep_misc<<<4689, 256, 0, stream>>>(features, captions, embed, b_ih, b_hh,
                                        ctxcat, bc, xs, h0,
                                        hs + (size_t)T_STEPS * B_ * H_, bar);
    prep_weights<<<42240, 256, 0, stream>>>(W_ih, W_hh, lin_W, Wx, Wc_cat, Whh, WlinB);

    // ---- ctxW: ONE GEMM, K=3072 computes hi@Wc_hi + lo@Wc_hi + hi@Wc_lo ----
    gemm_lds<64, 64><<<G4 / 64, 256, 0, stream>>>(ctxcat, Wc_cat, ctxW, nullptr, B_, G4, 3072, 0, 1);

    // ---- pre_x = xs @ Wx^T for all steps (M=1984, N=4096, K=512) ----
    gemm_lds<128, 128><<<(MPAD / 128) * (G4 / 128), 256, 0, stream>>>(
        xs, Wx, pre_x, nullptr, T_STEPS * B_, G4, E_, 0, MPAD / 128);

    // ---- recurrence: ONE persistent kernel, 512 threads, grid barrier per step ----
    recurrence<<<NREC, 512, 0, stream>>>(h0, hs, Whh, pre_x, ctxW, bc, bar);

    // ---- logits = hs @ lin_W^T + lin_b (M=1984, N=32000, K=1024) ----
    gemm_lds<128, 128><<<(MPAD / 128) * (V_ / 128), 256, 0, stream>>>(
        hs, WlinB, out, lin_b, T_STEPS * B_, V_, H_, 0, MPAD / 128);
}

// Round 3
// 1031.866 us; speedup vs baseline: 1.2511x; 1.1091x over previous
//
#include <hip/hip_runtime.h>
#include <hip/hip_bf16.h>
#include <stdint.h>

// Problem constants (VOCAB=32000, EMBED=512, HIDDEN=1024, ATT_L=64, MAX_LEN=32, BATCH=64)
#define T_STEPS 31        // MAX_LEN - 1
#define B_ 64
#define E_ 512
#define H_ 1024
#define G4 4096           // 4*HIDDEN gates
#define V_ 32000
#define MPAD 2048         // T_STEPS*B_=1984 padded to 128-multiple
#define NREC 64           // recurrence blocks = G4/64, one CU each

typedef __bf16 bf16x8_t __attribute__((ext_vector_type(8)));
typedef float f32x4_t __attribute__((ext_vector_type(4)));
typedef unsigned short u16x8_t __attribute__((ext_vector_type(8)));
using bf16 = __hip_bfloat16;

typedef const __attribute__((address_space(1))) unsigned int gas_u32;
typedef __attribute__((address_space(3))) unsigned int las_u32;

// Async global->LDS, 16B per lane. LDS dest must be wave-uniform base + lane*16
// (m104/m108: no per-lane scatter, no padding). Width=16 was the 517->874 TF step (m97).
__device__ __forceinline__ void async16(const bf16* g, bf16* l) {
    __builtin_amdgcn_global_load_lds((gas_u32*)(uintptr_t)g, (las_u32*)(uintptr_t)l, 16, 0, 0);
}

// ---------------------------------------------------------------------------
// m97-style GEMM: C = A @ BT^T (+bias) (+accumulate)
// 1D grid + bijective XCD swizzle (m204): consecutive swizzled wgids share
// one B-panel AND one XCD-L2 -> B fetched ~once per XCD.
// ---------------------------------------------------------------------------
template<int BM, int BN>
__global__ __launch_bounds__(256)
void gemm_lds(const bf16* __restrict__ A, const bf16* __restrict__ BT,
              float* __restrict__ C, const float* __restrict__ bias,
              int M, int N, int K, int accumulate, int mblocks)
{
    constexpr int BK = 32;
    constexpr int WM = BM / 2, WN = BN / 2;
    constexpr int MI = WM / 16, NI = WN / 16;
    constexpr int AV = (BM * BK) / (8 * 256);
    constexpr int BV = (BN * BK) / (8 * 256);
    static_assert(AV >= 1 && BV >= 1, "tile too small for staging");

    __shared__ bf16 As[BM * BK];
    __shared__ bf16 Bs[BN * BK];

    const int tid = threadIdx.x;
    const int lane = tid & 63;
    const int w = tid >> 6;
    const int wr = w >> 1, wc = w & 1;
    const int quad = lane >> 4, l16 = lane & 15;

    // bijective XCD swizzle (m204)
    const int nwg = gridDim.x;
    const int bid = blockIdx.x;
    const int q = nwg >> 3, r = nwg & 7;
    const int xcd = bid & 7, o = bid >> 3;
    const int wgid = (xcd < r ? xcd * (q + 1) : r * (q + 1) + (xcd - r) * q) + o;
    const int m0 = (wgid % mblocks) * BM;
    const int n0 = (wgid / mblocks) * BN;

    f32x4_t acc[MI][NI];
#pragma unroll
    for (int i = 0; i < MI; i++)
#pragma unroll
        for (int j = 0; j < NI; j++) acc[i][j] = f32x4_t{0.f, 0.f, 0.f, 0.f};

    for (int kt = 0; kt < K; kt += BK) {
#pragma unroll
        for (int v = 0; v < AV; v++) {
            int idx = tid + v * 256;
            int row = idx >> 2, col = (idx & 3) << 3;
            async16(A + (size_t)(m0 + row) * K + kt + col, As + idx * 8);
        }
#pragma unroll
        for (int v = 0; v < BV; v++) {
            int idx = tid + v * 256;
            int row = idx >> 2, col = (idx & 3) << 3;
            async16(BT + (size_t)(n0 + row) * K + kt + col, Bs + idx * 8);
        }
        __syncthreads();

        bf16x8_t af[MI], bfr[NI];
#pragma unroll
        for (int i = 0; i < MI; i++)
            af[i] = __builtin_bit_cast(bf16x8_t,
                *reinterpret_cast<const u16x8_t*>(&As[(wr * WM + i * 16 + l16) * BK + quad * 8]));
#pragma unroll
        for (int j = 0; j < NI; j++)
            bfr[j] = __builtin_bit_cast(bf16x8_t,
                *reinterpret_cast<const u16x8_t*>(&Bs[(wc * WN + j * 16 + l16) * BK + quad * 8]));
#pragma unroll
        for (int i = 0; i < MI; i++)
#pragma unroll
            for (int j = 0; j < NI; j++)
                acc[i][j] = __builtin_amdgcn_mfma_f32_16x16x32_bf16(af[i], bfr[j], acc[i][j], 0, 0, 0);
        __syncthreads();
    }

    // C/D layout: col=lane&15, row=quad*4+reg (m89)
#pragma unroll
    for (int i = 0; i < MI; i++) {
        int rbase = m0 + wr * WM + i * 16 + quad * 4;
#pragma unroll
        for (int j = 0; j < NI; j++) {
            int coln = n0 + wc * WN + j * 16 + l16;
            float badd = bias ? bias[coln] : 0.f;
#pragma unroll
            for (int r = 0; r < 4; r++) {
                int grow = rbase + r;
                if (grow < M) {
                    size_t ci = (size_t)grow * N + coln;
                    float val = acc[i][j][r] + badd;
                    if (accumulate) C[ci] += val; else C[ci] = val;
                }
            }
        }
    }
}

// ---------------------------------------------------------------------------
// Persistent recurrence v3: fence-free step barrier.
// Correctness argument: every hs[t] region is written exactly once (by agent-
// scope WRITE-THROUGH atomic stores -> data lands at L3, the device coherence
// point) and only read AFTER the barrier. No cache anywhere holds a stale copy
// of hs[t] before its write (first touch within this dispatch; kernel-launch
// acquire invalidated prior-iteration copies). Hence plain cached reads after
// the barrier are coherent WITHOUT any L2 invalidate/writeback fences.
// The barrier is: __syncthreads (drains every wave's store vmcnt) ->
// relaxed agent fetch_add -> relaxed agent poll -> __syncthreads.
// Benefits vs v2: no buffer_inv/buffer_wbl2 per step (poll no longer
// invalidates L2 every iteration!), L2 stays warm so the 8 blocks/XCD share
// h-line fills. Read side: all 32 h loads issued back-to-back into a static
// hr[32] register array (max MLP); pre_x[t+1] prefetched under the MFMA loop.
// ---------------------------------------------------------------------------
__global__ __launch_bounds__(512, 2)
void recurrence(const bf16* __restrict__ h0, bf16* __restrict__ hs,
                const bf16* __restrict__ Whh, const float* __restrict__ pre_x,
                const float* __restrict__ ctxW, const float* __restrict__ bc,
                int* __restrict__ bar)
{
    __shared__ bf16 Wl[64 * H_];          // 128 KiB swizzled Whh slice
    __shared__ float gates[64 * 68];      // 17 KiB raw acc exchange

    const int tid = threadIdx.x;
    const int lane = tid & 63;
    const int w = tid >> 6;               // 0..7
    const int wr = w >> 1;                // 0..3: 16-row batch strip
    const int wc = w & 1;                 // 0..1: 32-col gate strip
    const int quad = lane >> 4, l16 = lane & 15;
    const int n0 = blockIdx.x * 64;

    // ---- one-time: Whh slice -> LDS, reg-staged swizzled write (rule 21) ----
#pragma unroll 4
    for (int ck = tid; ck < 64 * 128; ck += 512) {          // 16B chunks
        int row = ck >> 7, c16 = ck & 127;
        u16x8_t v = *reinterpret_cast<const u16x8_t*>(Whh + (size_t)(n0 + row) * H_ + (c16 << 3));
        int byte = (row << 11) + (((c16 << 4)) ^ ((row & 7) << 4));
        *reinterpret_cast<u16x8_t*>(reinterpret_cast<char*>(Wl) + byte) = v;
    }

    // ---- pointwise-phase constants hoisted to registers ----
    const int pb = tid >> 3;              // batch row 0..63
    const int pj = tid & 7;               // gate-group pair 0..7 (j = pj*2, pj*2+1)
    const float* cxp = ctxW + (size_t)pb * G4 + n0 + pj * 8;
    const f32x4_t cx0 = *reinterpret_cast<const f32x4_t*>(cxp);
    const f32x4_t cx1 = *reinterpret_cast<const f32x4_t*>(cxp + 4);
    const f32x4_t bc0 = *reinterpret_cast<const f32x4_t*>(bc + n0 + pj * 8);
    const f32x4_t bc1 = *reinterpret_cast<const f32x4_t*>(bc + n0 + pj * 8 + 4);
    float creg0 = 0.f, creg1 = 0.f;       // cell state in registers

    // prefetch pre_x[0]
    const float* px0 = pre_x + (size_t)pb * G4 + n0 + pj * 8;
    f32x4_t p0 = *reinterpret_cast<const f32x4_t*>(px0);
    f32x4_t p1 = *reinterpret_cast<const f32x4_t*>(px0 + 4);

    __syncthreads();

    // lane-invariant address pieces
    const int arow = wr * 16 + l16;                   // A row (batch)
    const int r0 = wc * 32 + l16;                     // B row (gate col), r1 = r0+16
    const int xr = (r0 & 7) << 4;                     // (r0+16)&7 == r0&7
    const char* wl0 = reinterpret_cast<const char*>(Wl) + (r0 << 11);
    const char* wl1 = reinterpret_cast<const char*>(Wl) + ((r0 + 16) << 11);

    int target = NREC;
    for (int t = 0; t < T_STEPS; t++) {
        const bf16* hp = t ? hs + (size_t)(t - 1) * B_ * H_ : h0;
        const bf16* ha = hp + (size_t)arow * H_ + quad * 8;

        // issue ALL 32 h loads back-to-back -> 32 outstanding VMEM instrs/wave
        u16x8_t hr[32];
#pragma unroll
        for (int kk = 0; kk < 32; kk++)
            hr[kk] = *reinterpret_cast<const u16x8_t*>(ha + kk * 32);

        // prefetch NEXT step's pre_x (independent of h) -> hides under MFMA
        int tn = (t + 1 < T_STEPS) ? t + 1 : t;
        const float* pxn = pre_x + ((size_t)tn * B_ + pb) * G4 + n0 + pj * 8;
        f32x4_t p0n = *reinterpret_cast<const f32x4_t*>(pxn);
        f32x4_t p1n = *reinterpret_cast<const f32x4_t*>(pxn + 4);

        f32x4_t acc0 = {0.f, 0.f, 0.f, 0.f}, acc1 = {0.f, 0.f, 0.f, 0.f};
#pragma unroll
        for (int kk = 0; kk < 32; kk++) {
            int off = ((kk << 6) + (quad << 4)) ^ xr;
            bf16x8_t a  = __builtin_bit_cast(bf16x8_t, hr[kk]);
            bf16x8_t b0 = __builtin_bit_cast(bf16x8_t, *reinterpret_cast<const u16x8_t*>(wl0 + off));
            bf16x8_t b1 = __builtin_bit_cast(bf16x8_t, *reinterpret_cast<const u16x8_t*>(wl1 + off));
            acc0 = __builtin_amdgcn_mfma_f32_16x16x32_bf16(a, b0, acc0, 0, 0, 0);
            acc1 = __builtin_amdgcn_mfma_f32_16x16x32_bf16(a, b1, acc1, 0, 0, 0);
        }

        // raw acc -> LDS exchange (sum happens in pointwise phase, same order)
        {
            int rbase = wr * 16 + quad * 4;
#pragma unroll
            for (int r = 0; r < 4; r++) {
                gates[(rbase + r) * 68 + wc * 32 + l16]      = acc0[r];
                gates[(rbase + r) * 68 + wc * 32 + 16 + l16] = acc1[r];
            }
        }
        __syncthreads();

        // LSTM pointwise: thread -> (b=pb, jj=pj*2 / pj*2+1), c in registers
        {
            f32x4_t g0 = *reinterpret_cast<const f32x4_t*>(&gates[pb * 68 + pj * 8]);
            f32x4_t g1 = *reinterpret_cast<const f32x4_t*>(&gates[pb * 68 + pj * 8 + 4]);
            // exact original order: ((acc + bc) + pre_x) + ctxW
            float gi0 = g0[0] + bc0[0] + p0[0] + cx0[0];
            float gf0 = g0[1] + bc0[1] + p0[1] + cx0[1];
            float gg0 = g0[2] + bc0[2] + p0[2] + cx0[2];
            float go0 = g0[3] + bc0[3] + p0[3] + cx0[3];
            float gi1 = g1[0] + bc1[0] + p1[0] + cx1[0];
            float gf1 = g1[1] + bc1[1] + p1[1] + cx1[1];
            float gg1 = g1[2] + bc1[2] + p1[2] + cx1[2];
            float go1 = g1[3] + bc1[3] + p1[3] + cx1[3];

            float si0 = 1.f / (1.f + expf(-gi0));
            float sf0 = 1.f / (1.f + expf(-gf0));
            float so0 = 1.f / (1.f + expf(-go0));
            float cn0 = sf0 * creg0 + si0 * tanhf(gg0);
            float hn0 = so0 * tanhf(cn0);
            creg0 = cn0;

            float si1 = 1.f / (1.f + expf(-gi1));
            float sf1 = 1.f / (1.f + expf(-gf1));
            float so1 = 1.f / (1.f + expf(-go1));
            float cn1 = sf1 * creg1 + si1 * tanhf(gg1);
            float hn1 = so1 * tanhf(cn1);
            creg1 = cn1;

            // WRITE-THROUGH store (agent scope, lands at L3 = coherence point)
            int j0 = (n0 >> 2) + pj * 2;
            uint32_t hv = (uint32_t)__builtin_bit_cast(unsigned short, __float2bfloat16(hn0))
                        | ((uint32_t)__builtin_bit_cast(unsigned short, __float2bfloat16(hn1)) << 16);
            __hip_atomic_store(
                reinterpret_cast<uint32_t*>(&hs[((size_t)t * B_ + pb) * H_ + j0]),
                hv, __ATOMIC_RELAXED, __HIP_MEMORY_SCOPE_AGENT);
        }

        p0 = p0n; p1 = p1n;

        if (t < T_STEPS - 1) {
            // fence-free barrier: syncthreads drains each wave's store vmcnt
            __syncthreads();
            if (tid == 0) {
                __hip_atomic_fetch_add(bar, 1, __ATOMIC_RELAXED, __HIP_MEMORY_SCOPE_AGENT);
                while (__hip_atomic_load(bar, __ATOMIC_RELAXED, __HIP_MEMORY_SCOPE_AGENT) < target)
                    __builtin_amdgcn_s_sleep(1);
            }
            __syncthreads();
            target += NREC;
        }
        // last step: kernel-end release makes hs visible to the final GEMM
    }
}

// ---------------------------------------------------------------------------
// ONE fused prep kernel (ctx + all weight cvts + embed + bias + zeros + bar)
// Heavy per-block work (ctx) dispatched first; bulk weight cvts next.
// ---------------------------------------------------------------------------
__device__ __forceinline__ void cvt4(const float* __restrict__ src, bf16* hi, bf16* hi2, bf16* lo)
{
    f32x4_t v = *reinterpret_cast<const f32x4_t*>(src);
#pragma unroll
    for (int q = 0; q < 4; q++) {
        bf16 h = __float2bfloat16(v[q]);
        hi[q] = h;
        if (hi2) hi2[q] = h;
        if (lo) lo[q] = __float2bfloat16(v[q] - __bfloat162float(h));
    }
}

__global__ __launch_bounds__(256)
void prep_all(const float* __restrict__ features, const int* __restrict__ captions,
              const float* __restrict__ embed, const float* __restrict__ b_ih,
              const float* __restrict__ b_hh, const float* __restrict__ W_ih,
              const float* __restrict__ W_hh, const float* __restrict__ lin_W,
              bf16* __restrict__ ctxcat, float* __restrict__ bc, bf16* __restrict__ xs,
              bf16* __restrict__ Wx, bf16* __restrict__ Wc_cat, bf16* __restrict__ Whh,
              bf16* __restrict__ WlinB, bf16* __restrict__ h0, bf16* __restrict__ hs_tail,
              int* __restrict__ bar)
{
    const int blk = blockIdx.x, tid = threadIdx.x;
    if (blk < 64) {                       // ctx: A' = [hi | lo | hi] per batch row
        int b = blk;
        for (int j = tid; j < H_; j += 256) {
            float s = 0.f;
            const float* f = features + (size_t)b * 64 * H_ + j;
#pragma unroll
            for (int l = 0; l < 64; l++) s += f[(size_t)l * H_];
            bf16 h = __float2bfloat16(s);
            bf16 lo = __float2bfloat16(s - __bfloat162float(h));
            ctxcat[(size_t)b * 3072 + j] = h;
            ctxcat[(size_t)b * 3072 + 1024 + j] = lo;
            ctxcat[(size_t)b * 3072 + 2048 + j] = h;
        }
    } else if (blk < 42304) {             // weight conversions
        int wblk = blk - 64;
        if (wblk < 2048) {                // Wx: 4096x512 of W_ih, gate-permuted
            int item = wblk * 256 + tid;
            int e = item * 4; int r = e >> 9; int ci = e & (E_ - 1);
            int ro = (r & (H_ - 1)) * 4 + (r >> 10);
            cvt4(W_ih + (size_t)r * (E_ + H_) + ci, Wx + (size_t)ro * E_ + ci, nullptr, nullptr);
        } else if (wblk < 6144) {         // Wc: 4096x1024 slice, hi dup + lo residual
            int item = (wblk - 2048) * 256 + tid;
            int e = item * 4; int r = e >> 10; int ci = e & (H_ - 1);
            int ro = (r & (H_ - 1)) * 4 + (r >> 10);
            bf16* base = Wc_cat + (size_t)ro * 3072 + ci;
            cvt4(W_ih + (size_t)r * (E_ + H_) + E_ + ci, base, base + 1024, base + 2048);
        } else if (wblk < 10240) {        // Whh: 4096x1024, gate-permuted
            int item = (wblk - 6144) * 256 + tid;
            int e = item * 4; int r = e >> 10; int ci = e & (H_ - 1);
            int ro = (r & (H_ - 1)) * 4 + (r >> 10);
            cvt4(W_hh + (size_t)r * H_ + ci, Whh + (size_t)ro * H_ + ci, nullptr, nullptr);
        } else {                          // WlinB: 32000x1024, no permute
            long item = (long)(wblk - 10240) * 256 + tid;
            long e = item * 4; int r = (int)(e >> 10); int ci = (int)(e & (H_ - 1));
            cvt4(lin_W + (size_t)r * H_ + ci, WlinB + (size_t)r * H_ + ci, nullptr, nullptr);
        }
    } else if (blk < 46400) {             // gather_embed; pad rows zeroed
        int idx = (blk - 42304) * 256 + tid;
        int tb = idx >> 9, e = idx & (E_ - 1);
        float v = 0.f;
        if (tb < T_STEPS * B_) {
            int t = tb >> 6, b = tb & 63;
            v = embed[(size_t)captions[b * 32 + t] * E_ + e];
        }
        xs[idx] = __float2bfloat16(v);
    } else if (blk < 46416) {             // bias: bc[perm(g)] = b_ih[g]+b_hh[g]
        int g = (blk - 46400) * 256 + tid;
        bc[(g & (H_ - 1)) * 4 + (g >> 10)] = b_ih[g] + b_hh[g];
    } else if (blk < 46672) {             // zero h0 (64K elems)
        h0[(blk - 46416) * 256 + tid] = __float2bfloat16(0.f);
    } else if (blk < 46928) {             // zero hs pad tail (64K elems)
        hs_tail[(blk - 46672) * 256 + tid] = __float2bfloat16(0.f);
    } else if (tid == 0) {
        *bar = 0;
    }
}

// ---------------------------------------------------------------------------
extern "C" void kernel_launch(void* const* d_in, const int* in_sizes, int n_in,
                              void* d_out, int out_size, void* d_ws, size_t ws_size,
                              hipStream_t stream)
{
    (void)in_sizes; (void)n_in; (void)out_size; (void)ws_size;
    const float* features = (const float*)d_in[0];
    const int*   captions = (const int*)d_in[1];
    // d_in[2] lengths unused (full). d_in[8]/d_in[9] attn_W/b: dead (softmax over singleton dim).
    const float* embed    = (const float*)d_in[3];
    const float* W_ih     = (const float*)d_in[4];
    const float* W_hh     = (const float*)d_in[5];
    const float* b_ih     = (const float*)d_in[6];
    const float* b_hh     = (const float*)d_in[7];
    const float* lin_W    = (const float*)d_in[10];
    const float* lin_b    = (const float*)d_in[11];
    float* out = (float*)d_out;

    char* wp = (char*)d_ws;
    auto alloc = [&](size_t bytes) -> void* {
        void* p = (void*)wp;
        wp += (bytes + 255) & ~(size_t)255;
        return p;
    };
    bf16*  ctxcat = (bf16*)alloc((size_t)B_ * 3072 * 2);           // [hi | lo | hi]
    float* bc     = (float*)alloc((size_t)G4 * 4);
    bf16*  xs     = (bf16*)alloc((size_t)MPAD * E_ * 2);
    bf16*  Wx     = (bf16*)alloc((size_t)G4 * E_ * 2);             // gate-permuted rows
    bf16*  Wc_cat = (bf16*)alloc((size_t)G4 * 3072 * 2);           // [Wc_hi|Wc_hi|Wc_lo]
    bf16*  Whh    = (bf16*)alloc((size_t)G4 * H_ * 2);             // gate-permuted rows
    bf16*  WlinB  = (bf16*)alloc((size_t)V_ * H_ * 2);
    float* pre_x  = (float*)alloc((size_t)T_STEPS * B_ * G4 * 4);  // permuted cols
    float* ctxW   = (float*)alloc((size_t)B_ * G4 * 4);            // permuted cols
    bf16*  h0     = (bf16*)alloc((size_t)B_ * H_ * 2);             // zero initial h
    bf16*  hs     = (bf16*)alloc((size_t)MPAD * H_ * 2);
    int*   bar    = (int*)alloc(256);                              // grid barrier counter

    // ---- fused prep (1 launch) ----
    prep_all<<<46929, 256, 0, stream>>>(features, captions, embed, b_ih, b_hh,
                                        W_ih, W_hh, lin_W,
                                        ctxcat, bc, xs, Wx, Wc_cat, Whh, WlinB,
                                        h0, hs + (size_t)T_STEPS * B_ * H_, bar);

    // ---- ctxW: ONE GEMM, K=3072 computes hi@Wc_hi + lo@Wc_hi + hi@Wc_lo ----
    gemm_lds<64, 64><<<G4 / 64, 256, 0, stream>>>(ctxcat, Wc_cat, ctxW, nullptr, B_, G4, 3072, 0, 1);

    // ---- pre_x = xs @ Wx^T for all steps (M=1984, N=4096, K=512) ----
    gemm_lds<128, 128><<<(MPAD / 128) * (G4 / 128), 256, 0, stream>>>(
        xs, Wx, pre_x, nullptr, T_STEPS * B_, G4, E_, 0, MPAD / 128);

    // ---- recurrence: ONE persistent kernel, fence-free step barrier ----
    recurrence<<<NREC, 512, 0, stream>>>(h0, hs, Whh, pre_x, ctxW, bc, bar);

    // ---- logits = hs @ lin_W^T + lin_b (M=1984, N=32000, K=1024) ----
    gemm_lds<128, 128><<<(MPAD / 128) * (V_ / 128), 256, 0, stream>>>(
        hs, WlinB, out, lin_b, T_STEPS * B_, V_, H_, 0, MPAD / 128);
}